// Round 4
// baseline (141.478 us; speedup 1.0000x reference)
//
#include <hip/hip_runtime.h>

typedef short bf16x8 __attribute__((ext_vector_type(8)));
typedef float f32x4 __attribute__((ext_vector_type(4)));

#define B_    8
#define L_    500
#define LP    512
#define H_    16
#define DK    64
#define DM    1024
#define MP    4096
#define NT    8      // 512 / 64 keys per tile

static __device__ __forceinline__ unsigned short f2bf(float x) {
  unsigned u = __float_as_uint(x);
  u += 0x7fffu + ((u >> 16) & 1u);   // RNE
  return (unsigned short)(u >> 16);
}

static __device__ __forceinline__ void gload16(const void* g, void* l) {
  __builtin_amdgcn_global_load_lds(
      (const __attribute__((address_space(1))) void*)g,
      (__attribute__((address_space(3))) void*)l, 16, 0, 0);
}

// ---------- f32 -> bf16 for query/key/value, zero-pad rows 4000..4095 ----------
__global__ __launch_bounds__(256) void conv_x_kernel(
    const float* __restrict__ iq, const float* __restrict__ ik,
    const float* __restrict__ iv, unsigned short* __restrict__ X) {
  const int z = blockIdx.y;
  const float* src = (z == 0) ? iq : (z == 1) ? ik : iv;
  const size_t flat = (size_t)blockIdx.x * 256 + threadIdx.x;
  const size_t off = flat * 8;
  const int m = (int)(off >> 10);
  unsigned short o[8];
  if (m < 4000) {
    const float4 a = *(const float4*)(src + off);
    const float4 b = *(const float4*)(src + off + 4);
    o[0]=f2bf(a.x); o[1]=f2bf(a.y); o[2]=f2bf(a.z); o[3]=f2bf(a.w);
    o[4]=f2bf(b.x); o[5]=f2bf(b.y); o[6]=f2bf(b.z); o[7]=f2bf(b.w);
  } else {
#pragma unroll
    for (int i = 0; i < 8; ++i) o[i] = 0;
  }
  uint4 pk;
  pk.x = (unsigned)o[0] | ((unsigned)o[1] << 16);
  pk.y = (unsigned)o[2] | ((unsigned)o[3] << 16);
  pk.z = (unsigned)o[4] | ((unsigned)o[5] << 16);
  pk.w = (unsigned)o[6] | ((unsigned)o[7] << 16);
  *(uint4*)(X + (size_t)z * MP * DM + off) = pk;
}

// ---------- W (k,n) f32 -> Wt (n,k) bf16, LDS transpose (full 64x64 tile) ----------
__global__ __launch_bounds__(256) void conv_w_kernel(
    const float* __restrict__ wq, const float* __restrict__ wk,
    const float* __restrict__ wv, unsigned short* __restrict__ Wt) {
  const int z = blockIdx.y;
  const float* W = (z == 0) ? wq : (z == 1) ? wk : wv;
  const int k0 = (blockIdx.x >> 4) * 64;
  const int n0 = (blockIdx.x & 15) * 64;
  __shared__ float t[64][65];
  const int tid = threadIdx.x;
  const int row = tid >> 2;
  const int cb  = (tid & 3) * 16;
#pragma unroll
  for (int s = 0; s < 4; ++s) {
    const float4 v = *(const float4*)(W + (size_t)(k0 + row) * DM + n0 + cb + s * 4);
    t[row][cb + s * 4 + 0] = v.x; t[row][cb + s * 4 + 1] = v.y;
    t[row][cb + s * 4 + 2] = v.z; t[row][cb + s * 4 + 3] = v.w;
  }
  __syncthreads();
  const int nr = tid >> 2;
  const int kb = (tid & 3) * 16;
#pragma unroll
  for (int s = 0; s < 2; ++s) {
    unsigned short o[8];
#pragma unroll
    for (int e = 0; e < 8; ++e) o[e] = f2bf(t[kb + s * 8 + e][nr]);
    uint4 pk;
    pk.x = (unsigned)o[0] | ((unsigned)o[1] << 16);
    pk.y = (unsigned)o[2] | ((unsigned)o[3] << 16);
    pk.z = (unsigned)o[4] | ((unsigned)o[5] << 16);
    pk.w = (unsigned)o[6] | ((unsigned)o[7] << 16);
    *(uint4*)(Wt + (size_t)z * DM * DM + (size_t)(n0 + nr) * DM + k0 + kb + s * 8) = pk;
  }
}

// ---------- fused QKV projection GEMM (m97 structure, XCD-swizzled) ----------
__global__ __launch_bounds__(256) void gemm_qkv_kernel(
    const unsigned short* __restrict__ X, const unsigned short* __restrict__ Wt,
    const float* __restrict__ bq, const float* __restrict__ bk,
    const float* __restrict__ bv,
    unsigned short* __restrict__ qo, unsigned short* __restrict__ ko,
    unsigned short* __restrict__ vo) {
  const int z = blockIdx.y;
  const unsigned short* A  = X  + (size_t)z * MP * DM;
  const unsigned short* Bw = Wt + (size_t)z * DM * DM;
  const float* bias = (z == 0) ? bq : (z == 1) ? bk : bv;
  unsigned short* out = (z == 0) ? qo : (z == 1) ? ko : vo;

  const int bid = blockIdx.x;
  const int xg = bid & 7, y = bid >> 3;
  const int tm = xg + 8 * (y >> 3);
  const int tn = y & 7;
  const int tid = threadIdx.x;
  const int lane = tid & 63, wid = tid >> 6;
  const int wr = wid >> 1, wc = wid & 1;
  const int lg = lane >> 4, lr = lane & 15;

  __shared__ unsigned short sA[2][128 * 32];
  __shared__ unsigned short sB[2][128 * 32];

  const int c0 = tid, c1 = tid + 256;
  const int ar0 = c0 >> 2, ak0 = (c0 & 3) * 8;
  const int ar1 = c1 >> 2, ak1 = (c1 & 3) * 8;
  const unsigned short* Ab = A  + (size_t)tm * 128 * DM;
  const unsigned short* Bb = Bw + (size_t)tn * 128 * DM;

  f32x4 acc[4][4];
#pragma unroll
  for (int i = 0; i < 4; ++i)
#pragma unroll
    for (int j = 0; j < 4; ++j) acc[i][j] = (f32x4){0.f, 0.f, 0.f, 0.f};

  gload16(Ab + (size_t)ar0 * DM + ak0, &sA[0][c0 * 8]);
  gload16(Ab + (size_t)ar1 * DM + ak1, &sA[0][c1 * 8]);
  gload16(Bb + (size_t)ar0 * DM + ak0, &sB[0][c0 * 8]);
  gload16(Bb + (size_t)ar1 * DM + ak1, &sB[0][c1 * 8]);
  asm volatile("s_waitcnt vmcnt(0)" ::: "memory");
  __syncthreads();

  int cur = 0;
  for (int t = 0; t < 32; ++t) {
    if (t < 31) {
      const int kn = (t + 1) * 32;
      gload16(Ab + (size_t)ar0 * DM + kn + ak0, &sA[cur ^ 1][c0 * 8]);
      gload16(Ab + (size_t)ar1 * DM + kn + ak1, &sA[cur ^ 1][c1 * 8]);
      gload16(Bb + (size_t)ar0 * DM + kn + ak0, &sB[cur ^ 1][c0 * 8]);
      gload16(Bb + (size_t)ar1 * DM + kn + ak1, &sB[cur ^ 1][c1 * 8]);
    }
    bf16x8 af[4], bfr[4];
#pragma unroll
    for (int s = 0; s < 4; ++s) {
      af[s]  = *(const bf16x8*)&sA[cur][(wr * 64 + s * 16 + lr) * 32 + lg * 8];
      bfr[s] = *(const bf16x8*)&sB[cur][(wc * 64 + s * 16 + lr) * 32 + lg * 8];
    }
#pragma unroll
    for (int i = 0; i < 4; ++i)
#pragma unroll
      for (int j = 0; j < 4; ++j)
        acc[i][j] = __builtin_amdgcn_mfma_f32_16x16x32_bf16(af[i], bfr[j], acc[i][j], 0, 0, 0);
    asm volatile("s_waitcnt vmcnt(0)" ::: "memory");
    __syncthreads();
    cur ^= 1;
  }

  const int nbase = tn * 128 + wc * 64 + lr;
  float bias4[4];
#pragma unroll
  for (int ns = 0; ns < 4; ++ns) bias4[ns] = bias[nbase + ns * 16];

#pragma unroll
  for (int ms = 0; ms < 4; ++ms) {
#pragma unroll
    for (int r = 0; r < 4; ++r) {
      const int m = tm * 128 + wr * 64 + ms * 16 + lg * 4 + r;
      if (m < 4000) {
        const unsigned batch = (unsigned)m / 500u;
        const int lrow = m - (int)batch * 500;
#pragma unroll
        for (int ns = 0; ns < 4; ++ns) {
          const int n = nbase + ns * 16;
          const int hh = n >> 6, d = n & 63;
          out[(((size_t)batch * H_ + hh) * LP + lrow) * DK + d] =
              f2bf(acc[ms][ns][r] + bias4[ns]);
        }
      }
    }
  }
}

// ---------- V [bh][l][d] -> Vt [bh][d][l], zero-fill l >= 500 ----------
__global__ __launch_bounds__(256) void transpose_v_kernel(
    const unsigned short* __restrict__ v, unsigned short* __restrict__ vt) {
  const int bh = blockIdx.y;
  const int l0 = blockIdx.x * 64;
  __shared__ unsigned short t[64][72];
  const int tid = threadIdx.x;
  const int lrw = tid >> 2, dc = (tid & 3) * 16;
  const int gl = l0 + lrw;
  if (gl < L_) {
    *(uint4*)&t[lrw][dc]     = *(const uint4*)(v + ((size_t)bh * LP + gl) * DK + dc);
    *(uint4*)&t[lrw][dc + 8] = *(const uint4*)(v + ((size_t)bh * LP + gl) * DK + dc + 8);
  } else {
    const uint4 zz = {0u, 0u, 0u, 0u};
    *(uint4*)&t[lrw][dc]     = zz;
    *(uint4*)&t[lrw][dc + 8] = zz;
  }
  __syncthreads();
  const int dr = tid >> 2, lcb = (tid & 3) * 16;
#pragma unroll
  for (int s = 0; s < 2; ++s) {
    unsigned short e[8];
#pragma unroll
    for (int i = 0; i < 8; ++i) e[i] = t[lcb + s * 8 + i][dr];
    uint4 o;
    o.x = (unsigned)e[0] | ((unsigned)e[1] << 16);
    o.y = (unsigned)e[2] | ((unsigned)e[3] << 16);
    o.z = (unsigned)e[4] | ((unsigned)e[5] << 16);
    o.w = (unsigned)e[6] | ((unsigned)e[7] << 16);
    *(uint4*)(vt + ((size_t)bh * DK + dr) * LP + l0 + lcb + s * 8) = o;
  }
}

// ---------- flash attention: swapped-operand MFMA, no K/V staging, barrier-free loop ----------
// S^T = mfma(A=K, B=Q): lane holds S^T[key=c*16+lg*4+r][q=lr] -> q-row is lane-local.
// PV:  O^T = mfma(A=V^T (global), B=P^T (per-wave LDS)): lane holds O^T[d=lg*4+r][q=lr].
__global__ __launch_bounds__(256) void attn_kernel(
    const unsigned short* __restrict__ q, const unsigned short* __restrict__ k,
    const unsigned short* __restrict__ vt, const float* __restrict__ rel,
    float* __restrict__ out) {
  const int id = blockIdx.x;           // XCD = id%8 = bh%8 -> per-XCD K/V L2 residency
  const int bh = id & 127, qc = id >> 7;
  const int b = bh >> 4, h = bh & 15;
  const int tid = threadIdx.x;
  const int lane = tid & 63, wid = tid >> 6;
  const int lg = lane >> 4, lr = lane & 15;

  __shared__ __attribute__((aligned(16))) unsigned short pl[4][16][72];  // [wid][q][key(+pad)]
  __shared__ float relb[576];

  const float LOG2E = 1.44269504f;
  const float SC = 0.125f * LOG2E;
  const int rbase = qc * 64 - 12;
  for (int i = tid; i < 575; i += 256) {
    int idx = rbase + i;
    idx = idx < 0 ? 0 : (idx > 998 ? 998 : idx);
    relb[i] = rel[h * 999 + idx] * LOG2E;
  }
  __syncthreads();           // only barrier in the kernel

  // Q B-frag: col=q=lr, k=lg*8+e (two k-halves)
  const int qrow = qc * 64 + wid * 16 + lr;
  const unsigned short* qp = q + ((size_t)bh * LP + qrow) * DK + lg * 8;
  const bf16x8 qf0 = *(const bf16x8*)qp;
  const bf16x8 qf1 = *(const bf16x8*)(qp + 32);

  // direct-global fragment bases
  const unsigned short* kfb = k  + (size_t)bh * LP * DK + (size_t)lr * DK + lg * 8;
  const unsigned short* vfb = vt + (size_t)bh * DK * LP + (size_t)lr * LP + lg * 8;

  f32x4 o[4];
#pragma unroll
  for (int d = 0; d < 4; ++d) o[d] = (f32x4){0.f, 0.f, 0.f, 0.f};
  float mrun = -1e30f, lrun = 0.f;
  const int qin = wid * 16 + lr;

  for (int t = 0; t < NT; ++t) {
    // K A-frags: K[t*64 + c*16 + lr][half*32 + lg*8 ..+8)
    bf16x8 kf[4][2];
#pragma unroll
    for (int c = 0; c < 4; ++c) {
      const unsigned short* kp = kfb + (size_t)(t * 64 + c * 16) * DK;
      kf[c][0] = *(const bf16x8*)kp;
      kf[c][1] = *(const bf16x8*)(kp + 32);
    }
    // V^T A-frags (issued early; consumed after softmax): V^T[db*16+lr][t*64+kc*32+lg*8]
    bf16x8 vf[2][4];
#pragma unroll
    for (int kc = 0; kc < 2; ++kc)
#pragma unroll
      for (int db = 0; db < 4; ++db)
        vf[kc][db] = *(const bf16x8*)(vfb + (size_t)(db * 16) * LP + t * 64 + kc * 32);

    // S^T blocks
    f32x4 s[4];
#pragma unroll
    for (int c = 0; c < 4; ++c) {
      s[c] = (f32x4){0.f, 0.f, 0.f, 0.f};
      s[c] = __builtin_amdgcn_mfma_f32_16x16x32_bf16(kf[c][0], qf0, s[c], 0, 0, 0);
      s[c] = __builtin_amdgcn_mfma_f32_16x16x32_bf16(kf[c][1], qf1, s[c], 0, 0, 0);
    }

    // scores + bias (log2 domain); lane-local q-row
    float sc[4][4];
#pragma unroll
    for (int c = 0; c < 4; ++c) {
      const int bidx = qin - t * 64 - c * 16 - lg * 4 + 511;
#pragma unroll
      for (int r = 0; r < 4; ++r)
        sc[c][r] = s[c][r] * SC + relb[bidx - r];
    }
    if (t == NT - 1) {
#pragma unroll
      for (int c = 0; c < 4; ++c)
#pragma unroll
        for (int r = 0; r < 4; ++r)
          if (448 + c * 16 + lg * 4 + r >= L_) sc[c][r] = -1e30f;
    }

    // in-lane max of 16 + defer-max
    float m01 = fmaxf(fmaxf(sc[0][0], sc[0][1]), fmaxf(sc[0][2], sc[0][3]));
    float m11 = fmaxf(fmaxf(sc[1][0], sc[1][1]), fmaxf(sc[1][2], sc[1][3]));
    float m21 = fmaxf(fmaxf(sc[2][0], sc[2][1]), fmaxf(sc[2][2], sc[2][3]));
    float m31 = fmaxf(fmaxf(sc[3][0], sc[3][1]), fmaxf(sc[3][2], sc[3][3]));
    const float mloc = fmaxf(fmaxf(m01, m11), fmaxf(m21, m31));
    if (!__all(mloc - mrun <= 11.5f)) {
      float mx = fmaxf(mloc, mrun);
      mx = fmaxf(mx, __shfl_xor(mx, 16));
      mx = fmaxf(mx, __shfl_xor(mx, 32));
      const float alpha = exp2f(mrun - mx);
      mrun = mx;
      lrun *= alpha;
#pragma unroll
      for (int d = 0; d < 4; ++d) {
        o[d][0] *= alpha; o[d][1] *= alpha; o[d][2] *= alpha; o[d][3] *= alpha;
      }
    }

    // P = exp2(sc - mrun); pack 4 bf16 per c-block, one b64 LDS write each
    float rs = 0.f;
#pragma unroll
    for (int c = 0; c < 4; ++c) {
      float p0 = exp2f(sc[c][0] - mrun);
      float p1 = exp2f(sc[c][1] - mrun);
      float p2 = exp2f(sc[c][2] - mrun);
      float p3 = exp2f(sc[c][3] - mrun);
      rs += (p0 + p1) + (p2 + p3);
      uint2 w;
      w.x = (unsigned)f2bf(p0) | ((unsigned)f2bf(p1) << 16);
      w.y = (unsigned)f2bf(p2) | ((unsigned)f2bf(p3) << 16);
      *(uint2*)&pl[wid][lr][c * 16 + lg * 4] = w;
    }
    rs += __shfl_xor(rs, 16);
    rs += __shfl_xor(rs, 32);
    lrun += rs;

    // PV: B-frag = P^T from per-wave LDS (b128), A-frag = V^T (regs)
#pragma unroll
    for (int kc = 0; kc < 2; ++kc) {
      const bf16x8 pf = *(const bf16x8*)&pl[wid][lr][kc * 32 + lg * 8];
#pragma unroll
      for (int db = 0; db < 4; ++db)
        o[db] = __builtin_amdgcn_mfma_f32_16x16x32_bf16(vf[kc][db], pf, o[db], 0, 0, 0);
    }
  }

  // epilogue: lane owns q=qrow, d = db*16 + lg*4 + (0..3) -> float4 stores
  if (qrow < L_) {
    const float inv = 1.0f / lrun;
    float* op = out + ((size_t)b * L_ + qrow) * DM + h * DK + lg * 4;
#pragma unroll
    for (int db = 0; db < 4; ++db) {
      float4 v;
      v.x = o[db][0] * inv; v.y = o[db][1] * inv;
      v.z = o[db][2] * inv; v.w = o[db][3] * inv;
      *(float4*)(op + db * 16) = v;
    }
  }
}

extern "C" void kernel_launch(void* const* d_in, const int* in_sizes, int n_in,
                              void* d_out, int out_size, void* d_ws, size_t ws_size,
                              hipStream_t stream) {
  const float* iq  = (const float*)d_in[0];
  const float* ik  = (const float*)d_in[1];
  const float* iv  = (const float*)d_in[2];
  const float* wq  = (const float*)d_in[3];
  const float* bq  = (const float*)d_in[4];
  const float* wk  = (const float*)d_in[5];
  const float* bk  = (const float*)d_in[6];
  const float* wv  = (const float*)d_in[7];
  const float* bv  = (const float*)d_in[8];
  const float* rel = (const float*)d_in[9];
  float* out = (float*)d_out;

  char* w = (char*)d_ws;
  unsigned short* X   = (unsigned short*)(w);                 // [3][4096][1024] bf16
  unsigned short* Wt  = (unsigned short*)(w + 25165824);      // [3][1024][1024] bf16 (n,k)
  unsigned short* qb  = (unsigned short*)(w + 31457280);      // [128][512][64] bf16
  unsigned short* kb  = (unsigned short*)(w + 39845888);
  unsigned short* vb  = (unsigned short*)(w + 48234496);
  unsigned short* vtb = (unsigned short*)(w);                 // [128][64][512], overlaps X (dead)

  conv_x_kernel<<<dim3(2048, 3), 256, 0, stream>>>(iq, ik, iv, X);
  conv_w_kernel<<<dim3(256, 3), 256, 0, stream>>>(wq, wk, wv, Wt);
  gemm_qkv_kernel<<<dim3(256, 3), 256, 0, stream>>>(X, Wt, bq, bk, bv, qb, kb, vb);
  transpose_v_kernel<<<dim3(8, 128), 256, 0, stream>>>(vb, vtb);
  attn_kernel<<<1024, 256, 0, stream>>>(qb, kb, vtb, rel, out);
}

// Round 5
// 90.906 us; speedup vs baseline: 1.5563x; 1.5563x over previous
//
#include <hip/hip_runtime.h>

typedef short bf16x8 __attribute__((ext_vector_type(8)));
typedef float f32x4 __attribute__((ext_vector_type(4)));
typedef unsigned uint4v __attribute__((ext_vector_type(4)));

#define B_    8
#define L_    500
#define LP    512
#define H_    16
#define DK    64
#define DM    1024
#define MP    4096
#define NT    8      // 512 / 64 keys per tile

static __device__ __forceinline__ unsigned short f2bf(float x) {
  unsigned u = __float_as_uint(x);
  u += 0x7fffu + ((u >> 16) & 1u);   // RNE
  return (unsigned short)(u >> 16);
}

static __device__ __forceinline__ unsigned cvtpk(float lo, float hi) {
  unsigned r;
  asm("v_cvt_pk_bf16_f32 %0, %1, %2" : "=v"(r) : "v"(lo), "v"(hi));
  return r;
}

static __device__ __forceinline__ void gload16(const void* g, void* l) {
  __builtin_amdgcn_global_load_lds(
      (const __attribute__((address_space(1))) void*)g,
      (__attribute__((address_space(3))) void*)l, 16, 0, 0);
}

// ---------- f32 -> bf16 for query/key/value, zero-pad rows 4000..4095 ----------
__global__ __launch_bounds__(256) void conv_x_kernel(
    const float* __restrict__ iq, const float* __restrict__ ik,
    const float* __restrict__ iv, unsigned short* __restrict__ X) {
  const int z = blockIdx.y;
  const float* src = (z == 0) ? iq : (z == 1) ? ik : iv;
  const size_t flat = (size_t)blockIdx.x * 256 + threadIdx.x;
  const size_t off = flat * 8;
  const int m = (int)(off >> 10);
  unsigned short o[8];
  if (m < 4000) {
    const float4 a = *(const float4*)(src + off);
    const float4 b = *(const float4*)(src + off + 4);
    o[0]=f2bf(a.x); o[1]=f2bf(a.y); o[2]=f2bf(a.z); o[3]=f2bf(a.w);
    o[4]=f2bf(b.x); o[5]=f2bf(b.y); o[6]=f2bf(b.z); o[7]=f2bf(b.w);
  } else {
#pragma unroll
    for (int i = 0; i < 8; ++i) o[i] = 0;
  }
  uint4 pk;
  pk.x = (unsigned)o[0] | ((unsigned)o[1] << 16);
  pk.y = (unsigned)o[2] | ((unsigned)o[3] << 16);
  pk.z = (unsigned)o[4] | ((unsigned)o[5] << 16);
  pk.w = (unsigned)o[6] | ((unsigned)o[7] << 16);
  *(uint4*)(X + (size_t)z * MP * DM + off) = pk;
}

// ---------- W (k,n) f32 -> Wt (n,k) bf16, LDS transpose (full 64x64 tile) ----------
__global__ __launch_bounds__(256) void conv_w_kernel(
    const float* __restrict__ wq, const float* __restrict__ wk,
    const float* __restrict__ wv, unsigned short* __restrict__ Wt) {
  const int z = blockIdx.y;
  const float* W = (z == 0) ? wq : (z == 1) ? wk : wv;
  const int k0 = (blockIdx.x >> 4) * 64;
  const int n0 = (blockIdx.x & 15) * 64;
  __shared__ float t[64][65];
  const int tid = threadIdx.x;
  const int row = tid >> 2;
  const int cb  = (tid & 3) * 16;
#pragma unroll
  for (int s = 0; s < 4; ++s) {
    const float4 v = *(const float4*)(W + (size_t)(k0 + row) * DM + n0 + cb + s * 4);
    t[row][cb + s * 4 + 0] = v.x; t[row][cb + s * 4 + 1] = v.y;
    t[row][cb + s * 4 + 2] = v.z; t[row][cb + s * 4 + 3] = v.w;
  }
  __syncthreads();
  const int nr = tid >> 2;
  const int kb = (tid & 3) * 16;
#pragma unroll
  for (int s = 0; s < 2; ++s) {
    unsigned short o[8];
#pragma unroll
    for (int e = 0; e < 8; ++e) o[e] = f2bf(t[kb + s * 8 + e][nr]);
    uint4 pk;
    pk.x = (unsigned)o[0] | ((unsigned)o[1] << 16);
    pk.y = (unsigned)o[2] | ((unsigned)o[3] << 16);
    pk.z = (unsigned)o[4] | ((unsigned)o[5] << 16);
    pk.w = (unsigned)o[6] | ((unsigned)o[7] << 16);
    *(uint4*)(Wt + (size_t)z * DM * DM + (size_t)(n0 + nr) * DM + k0 + kb + s * 8) = pk;
  }
}

// ---------- fused QKV projection GEMM (m97 structure, XCD-swizzled) ----------
__global__ __launch_bounds__(256) void gemm_qkv_kernel(
    const unsigned short* __restrict__ X, const unsigned short* __restrict__ Wt,
    const float* __restrict__ bq, const float* __restrict__ bk,
    const float* __restrict__ bv,
    unsigned short* __restrict__ qo, unsigned short* __restrict__ ko,
    unsigned short* __restrict__ vo) {
  const int z = blockIdx.y;
  const unsigned short* A  = X  + (size_t)z * MP * DM;
  const unsigned short* Bw = Wt + (size_t)z * DM * DM;
  const float* bias = (z == 0) ? bq : (z == 1) ? bk : bv;
  unsigned short* out = (z == 0) ? qo : (z == 1) ? ko : vo;

  const int bid = blockIdx.x;
  const int xg = bid & 7, y = bid >> 3;
  const int tm = xg + 8 * (y >> 3);
  const int tn = y & 7;
  const int tid = threadIdx.x;
  const int lane = tid & 63, wid = tid >> 6;
  const int wr = wid >> 1, wc = wid & 1;
  const int lg = lane >> 4, lr = lane & 15;

  __shared__ unsigned short sA[2][128 * 32];
  __shared__ unsigned short sB[2][128 * 32];

  const int c0 = tid, c1 = tid + 256;
  const int ar0 = c0 >> 2, ak0 = (c0 & 3) * 8;
  const int ar1 = c1 >> 2, ak1 = (c1 & 3) * 8;
  const unsigned short* Ab = A  + (size_t)tm * 128 * DM;
  const unsigned short* Bb = Bw + (size_t)tn * 128 * DM;

  f32x4 acc[4][4];
#pragma unroll
  for (int i = 0; i < 4; ++i)
#pragma unroll
    for (int j = 0; j < 4; ++j) acc[i][j] = (f32x4){0.f, 0.f, 0.f, 0.f};

  gload16(Ab + (size_t)ar0 * DM + ak0, &sA[0][c0 * 8]);
  gload16(Ab + (size_t)ar1 * DM + ak1, &sA[0][c1 * 8]);
  gload16(Bb + (size_t)ar0 * DM + ak0, &sB[0][c0 * 8]);
  gload16(Bb + (size_t)ar1 * DM + ak1, &sB[0][c1 * 8]);
  asm volatile("s_waitcnt vmcnt(0)" ::: "memory");
  __syncthreads();

  int cur = 0;
  for (int t = 0; t < 32; ++t) {
    if (t < 31) {
      const int kn = (t + 1) * 32;
      gload16(Ab + (size_t)ar0 * DM + kn + ak0, &sA[cur ^ 1][c0 * 8]);
      gload16(Ab + (size_t)ar1 * DM + kn + ak1, &sA[cur ^ 1][c1 * 8]);
      gload16(Bb + (size_t)ar0 * DM + kn + ak0, &sB[cur ^ 1][c0 * 8]);
      gload16(Bb + (size_t)ar1 * DM + kn + ak1, &sB[cur ^ 1][c1 * 8]);
    }
    bf16x8 af[4], bfr[4];
#pragma unroll
    for (int s = 0; s < 4; ++s) {
      af[s]  = *(const bf16x8*)&sA[cur][(wr * 64 + s * 16 + lr) * 32 + lg * 8];
      bfr[s] = *(const bf16x8*)&sB[cur][(wc * 64 + s * 16 + lr) * 32 + lg * 8];
    }
#pragma unroll
    for (int i = 0; i < 4; ++i)
#pragma unroll
      for (int j = 0; j < 4; ++j)
        acc[i][j] = __builtin_amdgcn_mfma_f32_16x16x32_bf16(af[i], bfr[j], acc[i][j], 0, 0, 0);
    asm volatile("s_waitcnt vmcnt(0)" ::: "memory");
    __syncthreads();
    cur ^= 1;
  }

  const int nbase = tn * 128 + wc * 64 + lr;
  float bias4[4];
#pragma unroll
  for (int ns = 0; ns < 4; ++ns) bias4[ns] = bias[nbase + ns * 16];

#pragma unroll
  for (int ms = 0; ms < 4; ++ms) {
#pragma unroll
    for (int r = 0; r < 4; ++r) {
      const int m = tm * 128 + wr * 64 + ms * 16 + lg * 4 + r;
      if (m < 4000) {
        const unsigned batch = (unsigned)m / 500u;
        const int lrow = m - (int)batch * 500;
#pragma unroll
        for (int ns = 0; ns < 4; ++ns) {
          const int n = nbase + ns * 16;
          const int hh = n >> 6, d = n & 63;
          out[(((size_t)batch * H_ + hh) * LP + lrow) * DK + d] =
              f2bf(acc[ms][ns][r] + bias4[ns]);
        }
      }
    }
  }
}

// ---------- V [bh][l][d] -> Vt [bh][d][l], zero-fill l >= 500 ----------
__global__ __launch_bounds__(256) void transpose_v_kernel(
    const unsigned short* __restrict__ v, unsigned short* __restrict__ vt) {
  const int bh = blockIdx.y;
  const int l0 = blockIdx.x * 64;
  __shared__ unsigned short t[64][72];
  const int tid = threadIdx.x;
  const int lrw = tid >> 2, dc = (tid & 3) * 16;
  const int gl = l0 + lrw;
  if (gl < L_) {
    *(uint4*)&t[lrw][dc]     = *(const uint4*)(v + ((size_t)bh * LP + gl) * DK + dc);
    *(uint4*)&t[lrw][dc + 8] = *(const uint4*)(v + ((size_t)bh * LP + gl) * DK + dc + 8);
  } else {
    const uint4 zz = {0u, 0u, 0u, 0u};
    *(uint4*)&t[lrw][dc]     = zz;
    *(uint4*)&t[lrw][dc + 8] = zz;
  }
  __syncthreads();
  const int dr = tid >> 2, lcb = (tid & 3) * 16;
#pragma unroll
  for (int s = 0; s < 2; ++s) {
    unsigned short e[8];
#pragma unroll
    for (int i = 0; i < 8; ++i) e[i] = t[lcb + s * 8 + i][dr];
    uint4 o;
    o.x = (unsigned)e[0] | ((unsigned)e[1] << 16);
    o.y = (unsigned)e[2] | ((unsigned)e[3] << 16);
    o.z = (unsigned)e[4] | ((unsigned)e[5] << 16);
    o.w = (unsigned)e[6] | ((unsigned)e[7] << 16);
    *(uint4*)(vt + ((size_t)bh * DK + dr) * LP + l0 + lcb + s * 8) = o;
  }
}

// ---------- flash attention: staged K/V, swapped QK^T with sigma-permuted K rows,
//            P entirely in registers (zero P LDS traffic, zero redistribution) ----------
// QK^T (per 32-key chunk, half h): A-row o <- K[kc*32 + 8*(o>>2) + 4*h + (o&3)]
//   => lane (lr,lg) holds P for keys kc*32 + 8*lg + {0..7}, q = lr  == PV B-frag exactly.
// PV: O^T = mfma(A = V^T tile, B = P^T in-reg): lane gets O^T[d=db*16+lg*4+r][q=lr].
__global__ __launch_bounds__(256, 4) void attn_kernel(
    const unsigned short* __restrict__ q, const unsigned short* __restrict__ k,
    const unsigned short* __restrict__ vt, const float* __restrict__ rel,
    float* __restrict__ out) {
  const int id = blockIdx.x;           // XCD = id%8 = bh%8 -> per-XCD K/V L2 residency
  const int bh = id & 127, qc = id >> 7;
  const int b = bh >> 4, h = bh & 15;
  const int tid = threadIdx.x;
  const int lane = tid & 63, wid = tid >> 6;
  const int lg = lane >> 4, lr = lane & 15;

  __shared__ unsigned short kt[2][2][64][32];   // [buf][dhalf][key][d&31]
  __shared__ unsigned short vtt[2][2][64][32];  // [buf][keyhalf][d][key&31]
  __shared__ float relb[576];

  const float LOG2E = 1.44269504f;
  const float SC = 0.125f * LOG2E;
  const int rbase = qc * 64 - 12;
  for (int i = tid; i < 575; i += 256) {
    int idx = rbase + i;
    idx = idx < 0 ? 0 : (idx > 998 ? 998 : idx);
    relb[i] = rel[h * 999 + idx] * LOG2E;
  }

  // Q B-frag: col=q=lr, k=d
  const int qrow = qc * 64 + wid * 16 + lr;
  const unsigned short* qp = q + ((size_t)bh * LP + qrow) * DK + lg * 8;
  const bf16x8 qf0 = *(const bf16x8*)qp;
  const bf16x8 qf1 = *(const bf16x8*)(qp + 32);

  // staging assignments (whole block cooperates; 64B per thread per tile)
  const int kj = tid >> 2, dc = (tid & 3) * 16;
  const unsigned short* kgp = k + ((size_t)bh * LP + kj) * DK + dc;
  unsigned short* kls = &kt[0][dc >> 5][kj][dc & 31];
  const int vd = tid >> 2, vkg = (tid & 3) * 16;
  const unsigned short* vgp = vt + ((size_t)bh * DK + vd) * LP + vkg;
  unsigned short* vls = &vtt[0][vkg >> 5][vd][vkg & 31];

  const int sig0 = 8 * (lr >> 2) + (lr & 3);   // sigma base
  const int qin = wid * 16 + lr;

  f32x4 o[4];
#pragma unroll
  for (int d = 0; d < 4; ++d) o[d] = (f32x4){0.f, 0.f, 0.f, 0.f};
  float mrun = -1e30f, lrun = 0.f;

  uint4 ka0 = *(const uint4*)(kgp);
  uint4 ka1 = *(const uint4*)(kgp + 8);
  uint4 va0 = *(const uint4*)(vgp);
  uint4 va1 = *(const uint4*)(vgp + 8);

  for (int t = 0; t < NT; ++t) {
    const int buf = t & 1;
    *(uint4*)(kls + buf * 4096)     = ka0;
    *(uint4*)(kls + buf * 4096 + 8) = ka1;
    *(uint4*)(vls + buf * 4096)     = va0;
    *(uint4*)(vls + buf * 4096 + 8) = va1;
    __syncthreads();

    if (t < NT - 1) {   // next-tile register prefetch; hides under compute
      const size_t ko_ = (size_t)(t + 1) * 64 * DK;
      ka0 = *(const uint4*)(kgp + ko_);
      ka1 = *(const uint4*)(kgp + ko_ + 8);
      va0 = *(const uint4*)(vgp + (t + 1) * 64);
      va1 = *(const uint4*)(vgp + (t + 1) * 64 + 8);
    }

    // QK^T: sigma-permuted A rows
    f32x4 s[2][2];
#pragma unroll
    for (int kc = 0; kc < 2; ++kc)
#pragma unroll
      for (int hf = 0; hf < 2; ++hf) {
        const int sg = kc * 32 + hf * 4 + sig0;
        const bf16x8 a0 = *(const bf16x8*)&kt[buf][0][sg][lg * 8];
        const bf16x8 a1 = *(const bf16x8*)&kt[buf][1][sg][lg * 8];
        f32x4 ss = (f32x4){0.f, 0.f, 0.f, 0.f};
        ss = __builtin_amdgcn_mfma_f32_16x16x32_bf16(a0, qf0, ss, 0, 0, 0);
        ss = __builtin_amdgcn_mfma_f32_16x16x32_bf16(a1, qf1, ss, 0, 0, 0);
        s[kc][hf] = ss;
      }

    // scores + bias (log2 domain); lane q-row = lr; key = t*64+kc*32+8lg+4hf+r
    float sc[2][2][4];
#pragma unroll
    for (int kc = 0; kc < 2; ++kc)
#pragma unroll
      for (int hf = 0; hf < 2; ++hf) {
        const int bidx = qin - (t * 64 + kc * 32 + 8 * lg + 4 * hf) + 511;
#pragma unroll
        for (int r = 0; r < 4; ++r)
          sc[kc][hf][r] = s[kc][hf][r] * SC + relb[bidx - r];
      }
    if (t == NT - 1) {   // mask keys >= 500 (only kc=1: keys 480..511)
#pragma unroll
      for (int hf = 0; hf < 2; ++hf)
#pragma unroll
        for (int r = 0; r < 4; ++r)
          if (8 * lg + 4 * hf + r >= 20) sc[1][hf][r] = -1e30f;
    }

    // lane-local max over 16 + defer-max (T13)
    float m0 = fmaxf(fmaxf(sc[0][0][0], sc[0][0][1]), fmaxf(sc[0][0][2], sc[0][0][3]));
    float m1 = fmaxf(fmaxf(sc[0][1][0], sc[0][1][1]), fmaxf(sc[0][1][2], sc[0][1][3]));
    float m2 = fmaxf(fmaxf(sc[1][0][0], sc[1][0][1]), fmaxf(sc[1][0][2], sc[1][0][3]));
    float m3 = fmaxf(fmaxf(sc[1][1][0], sc[1][1][1]), fmaxf(sc[1][1][2], sc[1][1][3]));
    const float mloc = fmaxf(fmaxf(m0, m1), fmaxf(m2, m3));
    if (!__all(mloc - mrun <= 11.5f)) {
      float mx = fmaxf(mloc, mrun);
      mx = fmaxf(mx, __shfl_xor(mx, 16));
      mx = fmaxf(mx, __shfl_xor(mx, 32));
      const float alpha = exp2f(mrun - mx);
      mrun = mx;
      lrun *= alpha;
#pragma unroll
      for (int d = 0; d < 4; ++d) {
        o[d][0] *= alpha; o[d][1] *= alpha; o[d][2] *= alpha; o[d][3] *= alpha;
      }
    }

    // P = exp2(sc - mrun) -> packed bf16 B-frags entirely in registers
    float rs = 0.f;
    unsigned pw[2][4];
#pragma unroll
    for (int kc = 0; kc < 2; ++kc)
#pragma unroll
      for (int hf = 0; hf < 2; ++hf) {
        float p0 = exp2f(sc[kc][hf][0] - mrun);
        float p1 = exp2f(sc[kc][hf][1] - mrun);
        float p2 = exp2f(sc[kc][hf][2] - mrun);
        float p3 = exp2f(sc[kc][hf][3] - mrun);
        rs += (p0 + p1) + (p2 + p3);
        pw[kc][hf * 2 + 0] = cvtpk(p0, p1);
        pw[kc][hf * 2 + 1] = cvtpk(p2, p3);
      }
    rs += __shfl_xor(rs, 16);
    rs += __shfl_xor(rs, 32);
    lrun += rs;

    // PV: A = V^T slab (LDS), B = P^T (regs)
#pragma unroll
    for (int kc = 0; kc < 2; ++kc) {
      union { uint4v u; bf16x8 v; } cv;
      cv.u = (uint4v){pw[kc][0], pw[kc][1], pw[kc][2], pw[kc][3]};
      const bf16x8 pf = cv.v;
#pragma unroll
      for (int db = 0; db < 4; ++db) {
        const bf16x8 vf = *(const bf16x8*)&vtt[buf][kc][db * 16 + lr][lg * 8];
        o[db] = __builtin_amdgcn_mfma_f32_16x16x32_bf16(vf, pf, o[db], 0, 0, 0);
      }
    }
  }

  // epilogue: lane owns q=qrow, d = db*16 + lg*4 + (0..3) -> float4 stores
  if (qrow < L_) {
    const float inv = 1.0f / lrun;
    float* op = out + ((size_t)b * L_ + qrow) * DM + h * DK + lg * 4;
#pragma unroll
    for (int db = 0; db < 4; ++db) {
      float4 v;
      v.x = o[db][0] * inv; v.y = o[db][1] * inv;
      v.z = o[db][2] * inv; v.w = o[db][3] * inv;
      *(float4*)(op + db * 16) = v;
    }
  }
}

extern "C" void kernel_launch(void* const* d_in, const int* in_sizes, int n_in,
                              void* d_out, int out_size, void* d_ws, size_t ws_size,
                              hipStream_t stream) {
  const float* iq  = (const float*)d_in[0];
  const float* ik  = (const float*)d_in[1];
  const float* iv  = (const float*)d_in[2];
  const float* wq  = (const float*)d_in[3];
  const float* bq  = (const float*)d_in[4];
  const float* wk  = (const float*)d_in[5];
  const float* bk  = (const float*)d_in[6];
  const float* wv  = (const float*)d_in[7];
  const float* bv  = (const float*)d_in[8];
  const float* rel = (const float*)d_in[9];
  float* out = (float*)d_out;

  char* w = (char*)d_ws;
  unsigned short* X   = (unsigned short*)(w);                 // [3][4096][1024] bf16
  unsigned short* Wt  = (unsigned short*)(w + 25165824);      // [3][1024][1024] bf16 (n,k)
  unsigned short* qb  = (unsigned short*)(w + 31457280);      // [128][512][64] bf16
  unsigned short* kb  = (unsigned short*)(w + 39845888);
  unsigned short* vb  = (unsigned short*)(w + 48234496);
  unsigned short* vtb = (unsigned short*)(w);                 // [128][64][512], overlaps X (dead)

  conv_x_kernel<<<dim3(2048, 3), 256, 0, stream>>>(iq, ik, iv, X);
  conv_w_kernel<<<dim3(256, 3), 256, 0, stream>>>(wq, wk, wv, Wt);
  gemm_qkv_kernel<<<dim3(256, 3), 256, 0, stream>>>(X, Wt, bq, bk, bv, qb, kb, vb);
  transpose_v_kernel<<<dim3(8, 128), 256, 0, stream>>>(vb, vtb);
  attn_kernel<<<1024, 256, 0, stream>>>(qb, kb, vtb, rel, out);
}

// Round 6
// 85.159 us; speedup vs baseline: 1.6613x; 1.0675x over previous
//
#include <hip/hip_runtime.h>

typedef short bf16x8 __attribute__((ext_vector_type(8)));
typedef float f32x4 __attribute__((ext_vector_type(4)));
typedef unsigned uint4v __attribute__((ext_vector_type(4)));

#define B_    8
#define L_    500
#define LP    512
#define H_    16
#define DK    64
#define DM    1024
#define MP    4096
#define NT    8      // attn: 512 / 64 keys per tile

static __device__ __forceinline__ unsigned short f2bf(float x) {
  unsigned u = __float_as_uint(x);
  u += 0x7fffu + ((u >> 16) & 1u);   // RNE
  return (unsigned short)(u >> 16);
}

static __device__ __forceinline__ unsigned cvtpk(float lo, float hi) {
  unsigned r;
  asm("v_cvt_pk_bf16_f32 %0, %1, %2" : "=v"(r) : "v"(lo), "v"(hi));
  return r;
}

static __device__ __forceinline__ void gload16(const void* g, void* l) {
  __builtin_amdgcn_global_load_lds(
      (const __attribute__((address_space(1))) void*)g,
      (__attribute__((address_space(3))) void*)l, 16, 0, 0);
}

static __device__ __forceinline__ f32x4 MF(bf16x8 a, bf16x8 b, f32x4 c) {
  return __builtin_amdgcn_mfma_f32_16x16x32_bf16(a, b, c, 0, 0, 0);
}

// ---------- f32 -> bf16 for query/key/value, zero-pad rows 4000..4095 ----------
__global__ __launch_bounds__(256) void conv_x_kernel(
    const float* __restrict__ iq, const float* __restrict__ ik,
    const float* __restrict__ iv, unsigned short* __restrict__ X) {
  const int z = blockIdx.y;
  const float* src = (z == 0) ? iq : (z == 1) ? ik : iv;
  const size_t flat = (size_t)blockIdx.x * 256 + threadIdx.x;
  const size_t off = flat * 8;
  const int m = (int)(off >> 10);
  unsigned short o[8];
  if (m < 4000) {
    const float4 a = *(const float4*)(src + off);
    const float4 b = *(const float4*)(src + off + 4);
    o[0]=f2bf(a.x); o[1]=f2bf(a.y); o[2]=f2bf(a.z); o[3]=f2bf(a.w);
    o[4]=f2bf(b.x); o[5]=f2bf(b.y); o[6]=f2bf(b.z); o[7]=f2bf(b.w);
  } else {
#pragma unroll
    for (int i = 0; i < 8; ++i) o[i] = 0;
  }
  uint4 pk;
  pk.x = (unsigned)o[0] | ((unsigned)o[1] << 16);
  pk.y = (unsigned)o[2] | ((unsigned)o[3] << 16);
  pk.z = (unsigned)o[4] | ((unsigned)o[5] << 16);
  pk.w = (unsigned)o[6] | ((unsigned)o[7] << 16);
  *(uint4*)(X + (size_t)z * MP * DM + off) = pk;
}

// ---------- W (k,n) f32 -> Wt (n,k) bf16, LDS transpose (full 64x64 tile) ----------
__global__ __launch_bounds__(256) void conv_w_kernel(
    const float* __restrict__ wq, const float* __restrict__ wk,
    const float* __restrict__ wv, unsigned short* __restrict__ Wt) {
  const int z = blockIdx.y;
  const float* W = (z == 0) ? wq : (z == 1) ? wk : wv;
  const int k0 = (blockIdx.x >> 4) * 64;
  const int n0 = (blockIdx.x & 15) * 64;
  __shared__ float t[64][65];
  const int tid = threadIdx.x;
  const int row = tid >> 2;
  const int cb  = (tid & 3) * 16;
#pragma unroll
  for (int s = 0; s < 4; ++s) {
    const float4 v = *(const float4*)(W + (size_t)(k0 + row) * DM + n0 + cb + s * 4);
    t[row][cb + s * 4 + 0] = v.x; t[row][cb + s * 4 + 1] = v.y;
    t[row][cb + s * 4 + 2] = v.z; t[row][cb + s * 4 + 3] = v.w;
  }
  __syncthreads();
  const int nr = tid >> 2;
  const int kb = (tid & 3) * 16;
#pragma unroll
  for (int s = 0; s < 2; ++s) {
    unsigned short o[8];
#pragma unroll
    for (int e = 0; e < 8; ++e) o[e] = f2bf(t[kb + s * 8 + e][nr]);
    uint4 pk;
    pk.x = (unsigned)o[0] | ((unsigned)o[1] << 16);
    pk.y = (unsigned)o[2] | ((unsigned)o[3] << 16);
    pk.z = (unsigned)o[4] | ((unsigned)o[5] << 16);
    pk.w = (unsigned)o[6] | ((unsigned)o[7] << 16);
    *(uint4*)(Wt + (size_t)z * DM * DM + (size_t)(n0 + nr) * DM + k0 + kb + s * 8) = pk;
  }
}

// ---------- fused QKV projection GEMM: 256x256 tile, BK=64, 8-phase schedule ----------
// A = X[m][k], B = Wt[n][k]; LDS swizzle: byte ^= (row&7)<<4 (involution, both sides)
#define BAR()   __builtin_amdgcn_s_barrier()
#define LGKM0() do { asm volatile("s_waitcnt lgkmcnt(0)" ::: "memory"); \
                     __builtin_amdgcn_sched_barrier(0); } while (0)
#define VM0()   asm volatile("s_waitcnt vmcnt(0)" ::: "memory")
#define PRIO1() __builtin_amdgcn_s_setprio(1)
#define PRIO0() __builtin_amdgcn_s_setprio(0)

#define HALF_STEP(BK_, KTS_, DOST_)                                              \
  {                                                                              \
    /* phase 1: A mi0-3 + B ni0-1; stage A-halves of next kt */                  \
    _Pragma("unroll") for (int mi = 0; mi < 4; ++mi) {                           \
      aF[mi][0] = rdA(BK_, mi, 0); aF[mi][1] = rdA(BK_, mi, 1); }                \
    _Pragma("unroll") for (int ni = 0; ni < 2; ++ni) {                           \
      bF[ni][0] = rdB(BK_, ni, 0); bF[ni][1] = rdB(BK_, ni, 1); }                \
    if (DOST_) { STAGE((&sA[1 - (BK_)][0][0]), GA0, KTS_);                       \
                 STAGE((&sA[1 - (BK_)][1][0]), GA1, KTS_); }                     \
    BAR(); LGKM0(); PRIO1();                                                     \
    _Pragma("unroll") for (int mi = 0; mi < 4; ++mi)                             \
      _Pragma("unroll") for (int ni = 0; ni < 2; ++ni) {                         \
        acc[mi][ni] = MF(aF[mi][0], bF[ni][0], acc[mi][ni]);                     \
        acc[mi][ni] = MF(aF[mi][1], bF[ni][1], acc[mi][ni]); }                   \
    PRIO0(); BAR();                                                              \
    /* phase 2: B ni2-3; stage B-half0 */                                        \
    _Pragma("unroll") for (int ni = 0; ni < 2; ++ni) {                           \
      bF2[ni][0] = rdB(BK_, 2 + ni, 0); bF2[ni][1] = rdB(BK_, 2 + ni, 1); }      \
    if (DOST_) { STAGE((&sB[1 - (BK_)][0][0]), GB0, KTS_); }                     \
    BAR(); LGKM0(); PRIO1();                                                     \
    _Pragma("unroll") for (int mi = 0; mi < 4; ++mi)                             \
      _Pragma("unroll") for (int ni = 0; ni < 2; ++ni) {                         \
        acc[mi][2 + ni] = MF(aF[mi][0], bF2[ni][0], acc[mi][2 + ni]);            \
        acc[mi][2 + ni] = MF(aF[mi][1], bF2[ni][1], acc[mi][2 + ni]); }          \
    PRIO0(); BAR();                                                              \
    /* phase 3: A mi4-7; stage B-half1 */                                        \
    _Pragma("unroll") for (int mi = 0; mi < 4; ++mi) {                           \
      aF[mi][0] = rdA(BK_, 4 + mi, 0); aF[mi][1] = rdA(BK_, 4 + mi, 1); }        \
    if (DOST_) { STAGE((&sB[1 - (BK_)][1][0]), GB1, KTS_); }                     \
    BAR(); LGKM0(); PRIO1();                                                     \
    _Pragma("unroll") for (int mi = 0; mi < 4; ++mi)                             \
      _Pragma("unroll") for (int ni = 0; ni < 2; ++ni) {                         \
        acc[4 + mi][2 + ni] = MF(aF[mi][0], bF2[ni][0], acc[4 + mi][2 + ni]);    \
        acc[4 + mi][2 + ni] = MF(aF[mi][1], bF2[ni][1], acc[4 + mi][2 + ni]); }  \
    PRIO0(); BAR();                                                              \
    /* phase 4: B ni0-1 re-read; vmcnt(0) gate for next-buf reads */             \
    _Pragma("unroll") for (int ni = 0; ni < 2; ++ni) {                           \
      bF[ni][0] = rdB(BK_, ni, 0); bF[ni][1] = rdB(BK_, ni, 1); }                \
    VM0();                                                                       \
    BAR(); LGKM0(); PRIO1();                                                     \
    _Pragma("unroll") for (int mi = 0; mi < 4; ++mi)                             \
      _Pragma("unroll") for (int ni = 0; ni < 2; ++ni) {                         \
        acc[4 + mi][ni] = MF(aF[mi][0], bF[ni][0], acc[4 + mi][ni]);             \
        acc[4 + mi][ni] = MF(aF[mi][1], bF[ni][1], acc[4 + mi][ni]); }           \
    PRIO0(); BAR();                                                              \
  }

__global__ __launch_bounds__(512, 2) void gemm_qkv_kernel(
    const unsigned short* __restrict__ X, const unsigned short* __restrict__ Wt,
    const float* __restrict__ bq, const float* __restrict__ bk,
    const float* __restrict__ bv,
    unsigned short* __restrict__ qo, unsigned short* __restrict__ ko,
    unsigned short* __restrict__ vo) {
  const int bid = blockIdx.x;          // 192 blocks; XCD = bid%8
  const int z = bid >> 6, r = bid & 63;
  const int xcd = r & 7, j = r >> 3;
  const int tm = (xcd & 3) * 4 + (j & 3);    // 0..15
  const int tn = (xcd >> 2) * 2 + (j >> 2);  // 0..3
  const unsigned short* A  = X  + (size_t)z * MP * DM;
  const unsigned short* Bw = Wt + (size_t)z * DM * DM;
  const float* bias = (z == 0) ? bq : (z == 1) ? bk : bv;
  unsigned short* out = (z == 0) ? qo : (z == 1) ? ko : vo;

  const int tid = threadIdx.x;
  const int lane = tid & 63, wid = tid >> 6;
  const int wr = wid >> 2, wcol = wid & 3;    // 2M x 4N waves
  const int lg = lane >> 4, lr = lane & 15;

  __shared__ __attribute__((aligned(16))) unsigned short sA[2][2][128 * 64];
  __shared__ __attribute__((aligned(16))) unsigned short sB[2][2][128 * 64];

  // staging: half-tile = 128 rows x 8 chunks(16B); thread covers chunks tid, tid+512.
  // source chunk = (ch&7) ^ (row&7)  [inverse swizzle]; LDS dest linear.
  const int ch0 = tid, ch1 = tid + 512;
  const int row0 = ch0 >> 3, row1 = ch1 >> 3;
  const size_t so0 = (size_t)row0 * DM + (size_t)(((ch0 & 7) ^ (row0 & 7)) * 8);
  const size_t so1 = (size_t)row1 * DM + (size_t)(((ch1 & 7) ^ (row1 & 7)) * 8);
  const int lo0 = ch0 * 8, lo1 = ch1 * 8;
  const unsigned short* GA0 = A  + (size_t)(tm * 256) * DM;
  const unsigned short* GA1 = GA0 + (size_t)128 * DM;
  const unsigned short* GB0 = Bw + (size_t)(tn * 256) * DM;
  const unsigned short* GB1 = GB0 + (size_t)128 * DM;

  auto STAGE = [&](unsigned short* L, const unsigned short* G, int kt) {
    gload16(G + so0 + kt * 64, L + lo0);
    gload16(G + so1 + kt * 64, L + lo1);
  };

  // swizzled ds_read: byte ^= (row&7)<<4; row&7 == lr&7 for all fragments
  const int swzb = (lr & 7) << 4;
  auto rdA = [&](int bk_, int mi, int kk) {
    const int ush = (mi * 16 + lr) * 64 + (((kk * 64 + lg * 16) ^ swzb) >> 1);
    return *(const bf16x8*)&sA[bk_][wr][ush];
  };
  auto rdB = [&](int bk_, int ni, int kk) {
    const int ush = ((wcol & 1) * 64 + ni * 16 + lr) * 64 +
                    (((kk * 64 + lg * 16) ^ swzb) >> 1);
    return *(const bf16x8*)&sB[bk_][wcol >> 1][ush];
  };

  f32x4 acc[8][4];
#pragma unroll
  for (int i = 0; i < 8; ++i)
#pragma unroll
    for (int jj = 0; jj < 4; ++jj) acc[i][jj] = (f32x4){0.f, 0.f, 0.f, 0.f};

  // prologue: kt0 -> buf0
  STAGE(&sA[0][0][0], GA0, 0);
  STAGE(&sA[0][1][0], GA1, 0);
  STAGE(&sB[0][0][0], GB0, 0);
  STAGE(&sB[0][1][0], GB1, 0);
  VM0();
  BAR();

  bf16x8 aF[4][2], bF[2][2], bF2[2][2];
  for (int i = 0; i < 8; ++i) {
    HALF_STEP(0, 2 * i + 1, true);       // compute kt=2i (buf0), stage kt+1 -> buf1
    HALF_STEP(1, 2 * i + 2, (i < 7));    // compute kt=2i+1 (buf1), stage kt+2 -> buf0
  }

  // epilogue: bias + scatter to [b][h][l(512)][64] bf16
  const int nb = tn * 256 + wcol * 64 + lr;
  float bias4[4];
#pragma unroll
  for (int ni = 0; ni < 4; ++ni) bias4[ni] = bias[nb + ni * 16];

#pragma unroll
  for (int mi = 0; mi < 8; ++mi) {
#pragma unroll
    for (int rr = 0; rr < 4; ++rr) {
      const int m = tm * 256 + wr * 128 + mi * 16 + lg * 4 + rr;
      if (m < 4000) {
        const unsigned batch = (unsigned)m / 500u;
        const int lrow = m - (int)batch * 500;
#pragma unroll
        for (int ni = 0; ni < 4; ++ni) {
          const int n = nb + ni * 16;
          const int hh = n >> 6, d = n & 63;
          out[(((size_t)batch * H_ + hh) * LP + lrow) * DK + d] =
              f2bf(acc[mi][ni][rr] + bias4[ni]);
        }
      }
    }
  }
}

// ---------- V [bh][l][d] -> Vt [bh][d][l], zero-fill l >= 500 ----------
__global__ __launch_bounds__(256) void transpose_v_kernel(
    const unsigned short* __restrict__ v, unsigned short* __restrict__ vt) {
  const int bh = blockIdx.y;
  const int l0 = blockIdx.x * 64;
  __shared__ unsigned short t[64][72];
  const int tid = threadIdx.x;
  const int lrw = tid >> 2, dc = (tid & 3) * 16;
  const int gl = l0 + lrw;
  if (gl < L_) {
    *(uint4*)&t[lrw][dc]     = *(const uint4*)(v + ((size_t)bh * LP + gl) * DK + dc);
    *(uint4*)&t[lrw][dc + 8] = *(const uint4*)(v + ((size_t)bh * LP + gl) * DK + dc + 8);
  } else {
    const uint4 zz = {0u, 0u, 0u, 0u};
    *(uint4*)&t[lrw][dc]     = zz;
    *(uint4*)&t[lrw][dc + 8] = zz;
  }
  __syncthreads();
  const int dr = tid >> 2, lcb = (tid & 3) * 16;
#pragma unroll
  for (int s = 0; s < 2; ++s) {
    unsigned short e[8];
#pragma unroll
    for (int i = 0; i < 8; ++i) e[i] = t[lcb + s * 8 + i][dr];
    uint4 o;
    o.x = (unsigned)e[0] | ((unsigned)e[1] << 16);
    o.y = (unsigned)e[2] | ((unsigned)e[3] << 16);
    o.z = (unsigned)e[4] | ((unsigned)e[5] << 16);
    o.w = (unsigned)e[6] | ((unsigned)e[7] << 16);
    *(uint4*)(vt + ((size_t)bh * DK + dr) * LP + l0 + lcb + s * 8) = o;
  }
}

// ---------- flash attention: staged K/V, swapped QK^T with sigma-permuted K rows,
//            P entirely in registers (zero P LDS traffic, zero redistribution) ----------
__global__ __launch_bounds__(256, 4) void attn_kernel(
    const unsigned short* __restrict__ q, const unsigned short* __restrict__ k,
    const unsigned short* __restrict__ vt, const float* __restrict__ rel,
    float* __restrict__ out) {
  const int id = blockIdx.x;           // XCD = id%8 = bh%8 -> per-XCD K/V L2 residency
  const int bh = id & 127, qc = id >> 7;
  const int b = bh >> 4, h = bh & 15;
  const int tid = threadIdx.x;
  const int lane = tid & 63, wid = tid >> 6;
  const int lg = lane >> 4, lr = lane & 15;

  __shared__ unsigned short kt[2][2][64][32];   // [buf][dhalf][key][d&31]
  __shared__ unsigned short vtt[2][2][64][32];  // [buf][keyhalf][d][key&31]
  __shared__ float relb[576];

  const float LOG2E = 1.44269504f;
  const float SC = 0.125f * LOG2E;
  const int rbase = qc * 64 - 12;
  for (int i = tid; i < 575; i += 256) {
    int idx = rbase + i;
    idx = idx < 0 ? 0 : (idx > 998 ? 998 : idx);
    relb[i] = rel[h * 999 + idx] * LOG2E;
  }

  const int qrow = qc * 64 + wid * 16 + lr;
  const unsigned short* qp = q + ((size_t)bh * LP + qrow) * DK + lg * 8;
  const bf16x8 qf0 = *(const bf16x8*)qp;
  const bf16x8 qf1 = *(const bf16x8*)(qp + 32);

  const int kj = tid >> 2, dc = (tid & 3) * 16;
  const unsigned short* kgp = k + ((size_t)bh * LP + kj) * DK + dc;
  unsigned short* kls = &kt[0][dc >> 5][kj][dc & 31];
  const int vd = tid >> 2, vkg = (tid & 3) * 16;
  const unsigned short* vgp = vt + ((size_t)bh * DK + vd) * LP + vkg;
  unsigned short* vls = &vtt[0][vkg >> 5][vd][vkg & 31];

  const int sig0 = 8 * (lr >> 2) + (lr & 3);   // sigma base
  const int qin = wid * 16 + lr;

  f32x4 o[4];
#pragma unroll
  for (int d = 0; d < 4; ++d) o[d] = (f32x4){0.f, 0.f, 0.f, 0.f};
  float mrun = -1e30f, lrun = 0.f;

  uint4 ka0 = *(const uint4*)(kgp);
  uint4 ka1 = *(const uint4*)(kgp + 8);
  uint4 va0 = *(const uint4*)(vgp);
  uint4 va1 = *(const uint4*)(vgp + 8);

  for (int t = 0; t < NT; ++t) {
    const int buf = t & 1;
    *(uint4*)(kls + buf * 4096)     = ka0;
    *(uint4*)(kls + buf * 4096 + 8) = ka1;
    *(uint4*)(vls + buf * 4096)     = va0;
    *(uint4*)(vls + buf * 4096 + 8) = va1;
    __syncthreads();

    if (t < NT - 1) {
      const size_t ko_ = (size_t)(t + 1) * 64 * DK;
      ka0 = *(const uint4*)(kgp + ko_);
      ka1 = *(const uint4*)(kgp + ko_ + 8);
      va0 = *(const uint4*)(vgp + (t + 1) * 64);
      va1 = *(const uint4*)(vgp + (t + 1) * 64 + 8);
    }

    f32x4 s[2][2];
#pragma unroll
    for (int kc = 0; kc < 2; ++kc)
#pragma unroll
      for (int hf = 0; hf < 2; ++hf) {
        const int sg = kc * 32 + hf * 4 + sig0;
        const bf16x8 a0 = *(const bf16x8*)&kt[buf][0][sg][lg * 8];
        const bf16x8 a1 = *(const bf16x8*)&kt[buf][1][sg][lg * 8];
        f32x4 ss = (f32x4){0.f, 0.f, 0.f, 0.f};
        ss = __builtin_amdgcn_mfma_f32_16x16x32_bf16(a0, qf0, ss, 0, 0, 0);
        ss = __builtin_amdgcn_mfma_f32_16x16x32_bf16(a1, qf1, ss, 0, 0, 0);
        s[kc][hf] = ss;
      }

    float sc[2][2][4];
#pragma unroll
    for (int kc = 0; kc < 2; ++kc)
#pragma unroll
      for (int hf = 0; hf < 2; ++hf) {
        const int bidx = qin - (t * 64 + kc * 32 + 8 * lg + 4 * hf) + 511;
#pragma unroll
        for (int r = 0; r < 4; ++r)
          sc[kc][hf][r] = s[kc][hf][r] * SC + relb[bidx - r];
      }
    if (t == NT - 1) {
#pragma unroll
      for (int hf = 0; hf < 2; ++hf)
#pragma unroll
        for (int r = 0; r < 4; ++r)
          if (8 * lg + 4 * hf + r >= 20) sc[1][hf][r] = -1e30f;
    }

    float m0 = fmaxf(fmaxf(sc[0][0][0], sc[0][0][1]), fmaxf(sc[0][0][2], sc[0][0][3]));
    float m1 = fmaxf(fmaxf(sc[0][1][0], sc[0][1][1]), fmaxf(sc[0][1][2], sc[0][1][3]));
    float m2 = fmaxf(fmaxf(sc[1][0][0], sc[1][0][1]), fmaxf(sc[1][0][2], sc[1][0][3]));
    float m3 = fmaxf(fmaxf(sc[1][1][0], sc[1][1][1]), fmaxf(sc[1][1][2], sc[1][1][3]));
    const float mloc = fmaxf(fmaxf(m0, m1), fmaxf(m2, m3));
    if (!__all(mloc - mrun <= 11.5f)) {
      float mx = fmaxf(mloc, mrun);
      mx = fmaxf(mx, __shfl_xor(mx, 16));
      mx = fmaxf(mx, __shfl_xor(mx, 32));
      const float alpha = exp2f(mrun - mx);
      mrun = mx;
      lrun *= alpha;
#pragma unroll
      for (int d = 0; d < 4; ++d) {
        o[d][0] *= alpha; o[d][1] *= alpha; o[d][2] *= alpha; o[d][3] *= alpha;
      }
    }

    float rs = 0.f;
    unsigned pw[2][4];
#pragma unroll
    for (int kc = 0; kc < 2; ++kc)
#pragma unroll
      for (int hf = 0; hf < 2; ++hf) {
        float p0 = exp2f(sc[kc][hf][0] - mrun);
        float p1 = exp2f(sc[kc][hf][1] - mrun);
        float p2 = exp2f(sc[kc][hf][2] - mrun);
        float p3 = exp2f(sc[kc][hf][3] - mrun);
        rs += (p0 + p1) + (p2 + p3);
        pw[kc][hf * 2 + 0] = cvtpk(p0, p1);
        pw[kc][hf * 2 + 1] = cvtpk(p2, p3);
      }
    rs += __shfl_xor(rs, 16);
    rs += __shfl_xor(rs, 32);
    lrun += rs;

#pragma unroll
    for (int kc = 0; kc < 2; ++kc) {
      union { uint4v u; bf16x8 v; } cv;
      cv.u = (uint4v){pw[kc][0], pw[kc][1], pw[kc][2], pw[kc][3]};
      const bf16x8 pf = cv.v;
#pragma unroll
      for (int db = 0; db < 4; ++db) {
        const bf16x8 vf = *(const bf16x8*)&vtt[buf][kc][db * 16 + lr][lg * 8];
        o[db] = __builtin_amdgcn_mfma_f32_16x16x32_bf16(vf, pf, o[db], 0, 0, 0);
      }
    }
  }

  if (qrow < L_) {
    const float inv = 1.0f / lrun;
    float* op = out + ((size_t)b * L_ + qrow) * DM + h * DK + lg * 4;
#pragma unroll
    for (int db = 0; db < 4; ++db) {
      float4 v;
      v.x = o[db][0] * inv; v.y = o[db][1] * inv;
      v.z = o[db][2] * inv; v.w = o[db][3] * inv;
      *(float4*)(op + db * 16) = v;
    }
  }
}

extern "C" void kernel_launch(void* const* d_in, const int* in_sizes, int n_in,
                              void* d_out, int out_size, void* d_ws, size_t ws_size,
                              hipStream_t stream) {
  const float* iq  = (const float*)d_in[0];
  const float* ik  = (const float*)d_in[1];
  const float* iv  = (const float*)d_in[2];
  const float* wq  = (const float*)d_in[3];
  const float* bq  = (const float*)d_in[4];
  const float* wk  = (const float*)d_in[5];
  const float* bk  = (const float*)d_in[6];
  const float* wv  = (const float*)d_in[7];
  const float* bv  = (const float*)d_in[8];
  const float* rel = (const float*)d_in[9];
  float* out = (float*)d_out;

  char* w = (char*)d_ws;
  unsigned short* X   = (unsigned short*)(w);                 // [3][4096][1024] bf16
  unsigned short* Wt  = (unsigned short*)(w + 25165824);      // [3][1024][1024] bf16 (n,k)
  unsigned short* qb  = (unsigned short*)(w + 31457280);      // [128][512][64] bf16
  unsigned short* kb  = (unsigned short*)(w + 39845888);
  unsigned short* vb  = (unsigned short*)(w + 48234496);
  unsigned short* vtb = (unsigned short*)(w);                 // [128][64][512], overlaps X (dead)

  conv_x_kernel<<<dim3(2048, 3), 256, 0, stream>>>(iq, ik, iv, X);
  conv_w_kernel<<<dim3(256, 3), 256, 0, stream>>>(wq, wk, wv, Wt);
  gemm_qkv_kernel<<<192, 512, 0, stream>>>(X, Wt, bq, bk, bv, qb, kb, vb);
  transpose_v_kernel<<<dim3(8, 128), 256, 0, stream>>>(vb, vtb);
  attn_kernel<<<1024, 256, 0, stream>>>(qb, kb, vtb, rel, out);
}